// Round 8
// baseline (358.659 us; speedup 1.0000x reference)
//
#include <hip/hip_runtime.h>
#include <hip/hip_bf16.h>

#define NCLS   100000
#define NPAD   100096   // 391 * 256
#define BATCH  1024
#define EDIM   512

#define COS_M_  0.8775825618903728f
#define SIN_M_  0.479425538604203f
#define TH_     (-0.8775825618903728f)
#define MM_     0.2397127693021015f
#define SCALE_  64.0f

typedef __attribute__((ext_vector_type(8))) short short8;
typedef __attribute__((ext_vector_type(4))) float f32x4;

__device__ __forceinline__ ushort f2bf(float f) {
    uint u = __float_as_uint(f);
    u += 0x7fffu + ((u >> 16) & 1u);
    return (ushort)(u >> 16);
}

// One 64-lane wave per row: L2-normalize 512 f32 -> 512 bf16.
__global__ __launch_bounds__(256) void norm_rows_kernel(
    const float* __restrict__ in, ushort* __restrict__ out,
    int rows, int padrows)
{
    int gw   = (int)((blockIdx.x * blockDim.x + threadIdx.x) >> 6);
    int lane = (int)(threadIdx.x & 63);
    if (gw >= padrows) return;
    ushort* op = out + (size_t)gw * EDIM + lane * 8;
    if (gw >= rows) {
        uint4 z = make_uint4(0u, 0u, 0u, 0u);
        *(uint4*)op = z;
        return;
    }
    const float* ip = in + (size_t)gw * EDIM + lane * 8;
    float4 x0 = *(const float4*)ip;
    float4 x1 = *(const float4*)(ip + 4);
    float ss = x0.x*x0.x + x0.y*x0.y + x0.z*x0.z + x0.w*x0.w
             + x1.x*x1.x + x1.y*x1.y + x1.z*x1.z + x1.w*x1.w;
    #pragma unroll
    for (int off = 32; off; off >>= 1) ss += __shfl_xor(ss, off, 64);
    float inv = 1.0f / fmaxf(sqrtf(ss), 1e-12f);
    uint w0 = (uint)f2bf(x0.x*inv) | ((uint)f2bf(x0.y*inv) << 16);
    uint w1 = (uint)f2bf(x0.z*inv) | ((uint)f2bf(x0.w*inv) << 16);
    uint w2 = (uint)f2bf(x1.x*inv) | ((uint)f2bf(x1.y*inv) << 16);
    uint w3 = (uint)f2bf(x1.z*inv) | ((uint)f2bf(x1.w*inv) << 16);
    uint4 r; r.x = w0; r.y = w1; r.z = w2; r.w = w3;
    *(uint4*)op = r;
}

// Margin fixup on the 1024 (row, label) entries only.
__global__ __launch_bounds__(256) void fixup_labels_kernel(
    const int* __restrict__ labels, float* __restrict__ C)
{
    int row = (int)(blockIdx.x * blockDim.x + threadIdx.x);
    if (row >= BATCH) return;
    int lab = labels[row];
    float* p = C + (size_t)row * NCLS + lab;
    float c = *p * (1.0f / SCALE_);
    float s  = sqrtf(1.0f - c * c);
    float cm = c * COS_M_ - s * SIN_M_;
    cm = (c > TH_) ? cm : (c - MM_);
    *p = cm * SCALE_;
}

#define GLL16(g, s) __builtin_amdgcn_global_load_lds(                    \
    (const __attribute__((address_space(1))) void*)(g),                  \
    (__attribute__((address_space(3))) void*)(s), 16, 0, 0)

// ===== Persistent 256x256 GEMM, grid = 256 (1 block/CU), BK=32 ============
// 8 waves (2M x 4N), wave tile 128x64, acc[8][4]. Per K-tile: 2 phases
// {P0: RD B(nf0-3)+A(mf0-3) | stage A(tile+2) | bar | lgkm | 16 MFMA | bar}
// {P1: RD A(mf4-7)          | stage B(tile+2) | bar | lgkm | 16 MFMA | wait | bar}
// A tri-buffered (stage 2 ahead), B double-buffered. Counted vmcnt(4) in
// steady state, vmcnt(36) on the tile after a bcol epilogue (32 stores sit
// in the in-order queue between old and new loads). Each block processes
// 6-7 consecutive bcols with the pipeline warm across boundaries.
// LDS 80 KB; K-slot swizzle: slot ^= (row>>1)&3 (inverse pre-applied on the
// global source; per-lane constant on ds_read). Swapped-operand MFMA.
__global__ __launch_bounds__(512, 2) void gemm_arc_kernel(
    const ushort* __restrict__ A,
    const ushort* __restrict__ B,
    float* __restrict__ C)
{
    __shared__ __align__(16) ushort Als[3][256 * 32];  // 48 KB
    __shared__ __align__(16) ushort Bls[2][256 * 32];  // 32 KB

    const int t    = (int)threadIdx.x;          // 0..511
    const int lane = t & 63;
    const int w    = t >> 6;                    // 0..7
    const int wr   = w >> 2, wc = w & 3;        // 2M x 4N waves
    const int lr   = lane & 15, lg = lane >> 4;

    // XCD-local work split: xcd = bid&7; 32 blocks/XCD = 8 chunk-groups x 4
    // brows, so the 4 brow-siblings of a bcol chunk share one XCD's L2.
    const int bid  = (int)blockIdx.x;
    const int xcd  = bid & 7, idx = bid >> 3;
    const int brow = idx & 3;
    const int g    = xcd * 8 + (idx >> 2);      // 0..63
    const int cnt  = (g < 7) ? 7 : 6;           // 391 = 7*7 + 57*6
    const int start = (g < 7) ? 7 * g : 6 * g + 7;

    const f32x4 z4 = {0.f, 0.f, 0.f, 0.f};
    f32x4 acc[8][4];
    #pragma unroll
    for (int i = 0; i < 8; ++i)
        #pragma unroll
        for (int j = 0; j < 4; ++j) acc[i][j] = z4;

    // Staging: tile = 256 rows x 64 B; one GLL line = 512 thr x 16 B = 8 KB
    // = 128 rows; 2 lines per tile. Thread t: row t>>2, slot t&3; source
    // carries the inverse swizzle slot ^= (row>>1)&3.
    const int srow = t >> 2;
    const int scb  = ((t & 3) << 4) ^ (((t >> 3) & 3) << 4);
    const char* Ab = (const char*)A + ((size_t)(brow * 256 + srow)) * 1024 + scb;
    const char* Bb = (const char*)B + ((size_t)(start * 256 + srow)) * 1024 + scb;
    const uint ldsw = (uint)w * 1024;

    // ds_read: row R = base16 + lr, want slot lg -> swizzled slot
    // lg ^ ((R>>1)&3) = lg ^ ((lr>>1)&3): per-lane constant.
    const int koff  = (lg ^ ((lr >> 1) & 3)) << 4;
    const int abase = (wr * 128 + lr) * 64 + koff;   // + mf*1024
    const int bbase = (wc * 64  + lr) * 64 + koff;   // + nf*1024

#define STAGE_A(abuf, aoff) do {                                           \
        const char* s_ = Ab + (aoff);                                      \
        char* d_ = (char*)Als + (abuf) + ldsw;                             \
        GLL16(s_,              d_);                                        \
        GLL16(s_ + 128 * 1024, d_ + 8192);                                 \
    } while (0)
#define STAGE_B(bbuf, boff) do {                                           \
        const char* s_ = Bb + (boff);                                      \
        char* d_ = (char*)Bls + (bbuf) + ldsw;                             \
        GLL16(s_,              d_);                                        \
        GLL16(s_ + 128 * 1024, d_ + 8192);                                 \
    } while (0)
#define RD_A(dst, abuf, mf) \
    dst = *(const short8*)((const char*)Als + (abuf) + abase + (mf) * 1024)
#define RD_B(dst, bbuf, nf) \
    dst = *(const short8*)((const char*)Bls + (bbuf) + bbase + (nf) * 1024)
#define BAR()    __builtin_amdgcn_s_barrier()
#define LGKM0()  asm volatile("s_waitcnt lgkmcnt(0)" ::: "memory")
#define SCHED0() __builtin_amdgcn_sched_barrier(0)

    // prologue: tiles 0,1 (A->buf0,1; B->buf0,1); confirm tile 0.
    STAGE_A(0,     0);  STAGE_B(0,     0);
    STAGE_A(16384, 64); STAGE_B(16384, 64);
    asm volatile("s_waitcnt vmcnt(4)" ::: "memory");
    BAR();

    // A-buffer byte offsets for tiles S%3 == 0,1,2 at the current j.
    uint a0 = 0, a1 = 16384, a2 = 32768;

    short8 av[4], bv[4];
    #pragma unroll 1
    for (int j = 0; j < cnt; ++j) {
        const size_t bj = (size_t)j * 262144;
        const int morej = (j + 1 < cnt);
        #pragma unroll
        for (int S = 0; S < 16; ++S) {
            const uint aS  = (S % 3 == 0) ? a0 : (S % 3 == 1) ? a1 : a2;
            const uint aS2 = ((S + 2) % 3 == 0) ? a0 : ((S + 2) % 3 == 1) ? a1 : a2;
            const uint bS  = (uint)(S & 1) * 16384;
            // ---- P0: B(nf0-3) + A(mf0-3); stage A(tile+2) ----
            RD_B(bv[0], bS, 0); RD_B(bv[1], bS, 1);
            RD_B(bv[2], bS, 2); RD_B(bv[3], bS, 3);
            RD_A(av[0], aS, 0); RD_A(av[1], aS, 1);
            RD_A(av[2], aS, 2); RD_A(av[3], aS, 3);
            if (S < 14 || morej) STAGE_A(aS2, ((S + 2) & 15) * 64);
            BAR(); LGKM0(); SCHED0();
            __builtin_amdgcn_s_setprio(1);
            #pragma unroll
            for (int mi = 0; mi < 4; ++mi)
                #pragma unroll
                for (int ni = 0; ni < 4; ++ni)
                    acc[mi][ni] = __builtin_amdgcn_mfma_f32_16x16x32_bf16(
                        bv[ni], av[mi], acc[mi][ni], 0, 0, 0);
            __builtin_amdgcn_s_setprio(0);
            BAR();
            // ---- P1: A(mf4-7); stage B(tile+2); counted wait ----
            RD_A(av[0], aS, 4); RD_A(av[1], aS, 5);
            RD_A(av[2], aS, 6); RD_A(av[3], aS, 7);
            if (S < 14 || morej)
                STAGE_B(bS, bj + (S < 14 ? (size_t)(S + 2) * 64
                                         : 262144 + (size_t)((S + 2) & 15) * 64));
            BAR(); LGKM0(); SCHED0();
            __builtin_amdgcn_s_setprio(1);
            #pragma unroll
            for (int mi = 0; mi < 4; ++mi)
                #pragma unroll
                for (int ni = 0; ni < 4; ++ni)
                    acc[mi + 4][ni] = __builtin_amdgcn_mfma_f32_16x16x32_bf16(
                        bv[ni], av[mi], acc[mi + 4][ni], 0, 0, 0);
            __builtin_amdgcn_s_setprio(0);
            if (S == 0 && j > 0) {
                asm volatile("s_waitcnt vmcnt(36)" ::: "memory");
            } else if (S == 14 && !morej) {
                asm volatile("s_waitcnt vmcnt(0)" ::: "memory");
            } else if (!(S == 15 && !morej)) {
                asm volatile("s_waitcnt vmcnt(4)" ::: "memory");
            }
            if (S == 15) {
                // per-bcol epilogue: clamp+scale, dwordx4 stores (issued AFTER
                // the counted wait so the next tile's vmcnt(36) can skip them)
                const int mbase = brow * 256 + wr * 128;
                const int nb    = (start + j) * 256 + wc * 64;
                #pragma unroll
                for (int mf = 0; mf < 8; ++mf) {
                    const int grow = mbase + mf * 16 + lr;
                    float* crow = C + (size_t)grow * NCLS;
                    #pragma unroll
                    for (int nf = 0; nf < 4; ++nf) {
                        if (nb + nf * 16 < NCLS) {
                            f32x4 v = acc[mf][nf];
                            f32x4 o;
                            #pragma unroll
                            for (int q = 0; q < 4; ++q) {
                                float cc = fminf(fmaxf(v[q], -1.0f + 1e-7f),
                                                 1.0f - 1e-7f);
                                o[q] = cc * SCALE_;
                            }
                            *(f32x4*)&crow[nb + nf * 16 + lg * 4] = o;
                        }
                        acc[mf][nf] = z4;
                    }
                }
            }
            BAR();
        }
        // rotate A buffers: buffer of (j+1, S) = buffer of (j, S+1)
        uint tmp = a0; a0 = a1; a1 = a2; a2 = tmp;
    }
#undef STAGE_A
#undef STAGE_B
#undef RD_A
#undef RD_B
#undef BAR
#undef LGKM0
#undef SCHED0
}

extern "C" void kernel_launch(void* const* d_in, const int* in_sizes, int n_in,
                              void* d_out, int out_size, void* d_ws, size_t ws_size,
                              hipStream_t stream)
{
    const float* emb    = (const float*)d_in[0];
    const int*   labels = (const int*)d_in[1];
    const float* wgt    = (const float*)d_in[2];
    float*       out    = (float*)d_out;

    ushort* Ebf = (ushort*)d_ws;
    ushort* Wbf = (ushort*)((char*)d_ws + (size_t)BATCH * EDIM * 2);

    norm_rows_kernel<<<BATCH / 4, 256, 0, stream>>>(emb, Ebf, BATCH, BATCH);
    norm_rows_kernel<<<NPAD / 4, 256, 0, stream>>>(wgt, Wbf, NCLS, NPAD);

    gemm_arc_kernel<<<256, 512, 0, stream>>>(Ebf, Wbf, out);

    fixup_labels_kernel<<<BATCH / 256, 256, 0, stream>>>(labels, out);
}

// Round 9
// 223.640 us; speedup vs baseline: 1.6037x; 1.6037x over previous
//
#include <hip/hip_runtime.h>
#include <hip/hip_bf16.h>

#define NCLS   100000
#define NPAD   100096   // 782 * 128
#define BATCH  1024
#define EDIM   512

#define COS_M_  0.8775825618903728f
#define SIN_M_  0.479425538604203f
#define TH_     (-0.8775825618903728f)
#define MM_     0.2397127693021015f
#define SCALE_  64.0f

typedef __attribute__((ext_vector_type(8))) short short8;
typedef __attribute__((ext_vector_type(4))) float f32x4;

__device__ __forceinline__ ushort f2bf(float f) {
    // round-to-nearest-even f32 -> bf16
    uint u = __float_as_uint(f);
    u += 0x7fffu + ((u >> 16) & 1u);
    return (ushort)(u >> 16);
}

// One 64-lane wave per row: L2-normalize 512 f32 -> 512 bf16.
// Rows in [rows, padrows) are zero-filled (N-padding for the GEMM).
__global__ __launch_bounds__(256) void norm_rows_kernel(
    const float* __restrict__ in, ushort* __restrict__ out,
    int rows, int padrows)
{
    int gw   = (int)((blockIdx.x * blockDim.x + threadIdx.x) >> 6);
    int lane = (int)(threadIdx.x & 63);
    if (gw >= padrows) return;
    ushort* op = out + (size_t)gw * EDIM + lane * 8;
    if (gw >= rows) {
        uint4 z = make_uint4(0u, 0u, 0u, 0u);
        *(uint4*)op = z;
        return;
    }
    const float* ip = in + (size_t)gw * EDIM + lane * 8;
    float4 x0 = *(const float4*)ip;
    float4 x1 = *(const float4*)(ip + 4);
    float ss = x0.x*x0.x + x0.y*x0.y + x0.z*x0.z + x0.w*x0.w
             + x1.x*x1.x + x1.y*x1.y + x1.z*x1.z + x1.w*x1.w;
    #pragma unroll
    for (int off = 32; off; off >>= 1) ss += __shfl_xor(ss, off, 64);
    float inv = 1.0f / fmaxf(sqrtf(ss), 1e-12f);
    uint w0 = (uint)f2bf(x0.x*inv) | ((uint)f2bf(x0.y*inv) << 16);
    uint w1 = (uint)f2bf(x0.z*inv) | ((uint)f2bf(x0.w*inv) << 16);
    uint w2 = (uint)f2bf(x1.x*inv) | ((uint)f2bf(x1.y*inv) << 16);
    uint w3 = (uint)f2bf(x1.z*inv) | ((uint)f2bf(x1.w*inv) << 16);
    uint4 r; r.x = w0; r.y = w1; r.z = w2; r.w = w3;
    *(uint4*)op = r;
}

// Margin fixup: only the 1024 (row, label[row]) entries need the ArcFace
// margin. GEMM stored clamp(cos)*64; recover cos = v/64 (exact, pow2 scale),
// apply margin, rewrite.
__global__ __launch_bounds__(256) void fixup_labels_kernel(
    const int* __restrict__ labels, float* __restrict__ C)
{
    int row = (int)(blockIdx.x * blockDim.x + threadIdx.x);
    if (row >= BATCH) return;
    int lab = labels[row];
    float* p = C + (size_t)row * NCLS + lab;
    float c = *p * (1.0f / SCALE_);
    float s  = sqrtf(1.0f - c * c);
    float cm = c * COS_M_ - s * SIN_M_;
    cm = (c > TH_) ? cm : (c - MM_);
    *p = cm * SCALE_;
}

#define GLL16(g, s) __builtin_amdgcn_global_load_lds(                    \
    (const __attribute__((address_space(1))) void*)(g),                  \
    (__attribute__((address_space(3))) void*)(s), 16, 0, 0)

// 128x128 tile, BK=32, 4 waves (2x2), mfma_f32_16x16x32_bf16 (SWAPPED
// operands: lane's 4 acc regs = 4 consecutive N-cols -> dwordx4 C stores).
// Depth-3 circular LDS pipeline, counted vmcnt + raw s_barrier (loads for
// the next 2 K-tiles stay in flight across barriers). COMPUTE body is plain
// C++ (compiler schedules fine-grained lgkmcnt between ds_read and MFMA).
// XOR-swizzled K-slots, T1 XCD chunk swizzle, NT stores. Epilogue is
// clamp+scale only (margin via fixup_labels_kernel).
__global__ __launch_bounds__(256, 3) void gemm_arc_kernel(
    const ushort* __restrict__ A,
    const ushort* __restrict__ B,
    float* __restrict__ C)
{
    // 3 buffers x (A:8KB + B:8KB) = 48 KB -> 3 blocks/CU
    __shared__ __align__(16) ushort Als[3][128 * 32];
    __shared__ __align__(16) ushort Bls[3][128 * 32];

    const int t    = (int)threadIdx.x;
    const int lane = t & 63;
    const int w    = t >> 6;
    const int wrow = w >> 1, wcol = w & 1;
    const int lr   = lane & 15, lg = lane >> 4;

    // T1 bijective XCD swizzle: the 8 M-blocks sharing a B-tile land on ONE
    // XCD. nwg = 6256, %8 == 0.
    const int nwg  = (int)gridDim.x;
    const int cpx  = nwg >> 3;               // 782
    const int bid  = (int)blockIdx.x;
    const int swz  = (bid & 7) * cpx + (bid >> 3);
    const int brow = swz & 7;                // M-tile (0..7)
    const int bcol = swz >> 3;               // N-tile (0..781)

    const f32x4 z4 = {0.f, 0.f, 0.f, 0.f};
    f32x4 acc[4][4];
    #pragma unroll
    for (int i = 0; i < 4; ++i)
        #pragma unroll
        for (int j = 0; j < 4; ++j) acc[i][j] = z4;

    // staging: 256 threads x 16 B = 4 KB per instruction = 64 rows x 64 B.
    // LDS dest linear; global SOURCE byte offset carries the inverse K-slot
    // swizzle off' ^= ((row>>1)&3)<<4.
    const int srow = t >> 2;
    const int scb  = ((t & 3) * 16) ^ (((t >> 3) & 3) << 4);
    const char* Ab = (const char*)(A + ((size_t)brow * 128 + srow) * EDIM) + scb;
    const char* Bb = (const char*)(B + ((size_t)bcol * 128 + srow) * EDIM) + scb;
    const uint ldsw = (uint)w * 1024;        // wave-uniform LDS base (+lane*16 HW)

    // ds_read side: row R, byte (lg*16) ^ ((R>>1)&3)<<4; for R = base16+lr the
    // XOR term is the per-lane constant ((lr>>1)&3)<<4.
    const int kswz  = ((lr >> 1) & 3) << 4;
    const int aoff0 = (wrow * 64 + lr) * 64 + ((lg * 16) ^ kswz);
    const int boff0 = (wcol * 64 + lr) * 64 + ((lg * 16) ^ kswz);

#define STAGE(c, kt) do {                                                  \
        const char* a0 = Ab + (kt) * 64;                                   \
        const char* b0 = Bb + (kt) * 64;                                   \
        char* Ad = (char*)Als + (size_t)(c) * 8192 + ldsw;                 \
        char* Bd = (char*)Bls + (size_t)(c) * 8192 + ldsw;                 \
        GLL16(a0,                 Ad);                                     \
        GLL16(a0 + 64 * EDIM * 2, Ad + 4096);                              \
        GLL16(b0,                 Bd);                                     \
        GLL16(b0 + 64 * EDIM * 2, Bd + 4096);                              \
    } while (0)

// Swapped operands: mfma(bv, av) -> acc[mi][ni][reg] =
//   C[mbase + mi*16 + lr][nbase + ni*16 + lg*4 + reg]
#define COMPUTE(c) do {                                                    \
        const char* Ap = (const char*)Als + (size_t)(c) * 8192;            \
        const char* Bp = (const char*)Bls + (size_t)(c) * 8192;            \
        short8 av[4], bv[4];                                               \
        _Pragma("unroll")                                                  \
        for (int mi = 0; mi < 4; ++mi)                                     \
            av[mi] = *(const short8*)(Ap + aoff0 + mi * 1024);             \
        _Pragma("unroll")                                                  \
        for (int ni = 0; ni < 4; ++ni)                                     \
            bv[ni] = *(const short8*)(Bp + boff0 + ni * 1024);             \
        _Pragma("unroll")                                                  \
        for (int mi = 0; mi < 4; ++mi)                                     \
            _Pragma("unroll")                                              \
            for (int ni = 0; ni < 4; ++ni)                                 \
                acc[mi][ni] = __builtin_amdgcn_mfma_f32_16x16x32_bf16(     \
                    bv[ni], av[mi], acc[mi][ni], 0, 0, 0);                 \
    } while (0)

    // prologue: stage tiles 0,1 (8 loads in flight)
    STAGE(0, 0);
    STAGE(1, 1);

    // main loop: stage kt+2, wait ONLY for tile kt (vmcnt(8) leaves tiles
    // kt+1,kt+2 in flight across the barrier), compute kt.
    #pragma unroll
    for (int kt = 0; kt < 14; ++kt) {
        // protect buffer (kt+2)%3 (= (kt-1)%3) from overwrite until all waves
        // finished their ds_reads of it in COMPUTE(kt-1)
        asm volatile("s_waitcnt lgkmcnt(0)" ::: "memory");
        __builtin_amdgcn_s_barrier();
        STAGE((kt + 2) % 3, kt + 2);
        asm volatile("s_waitcnt vmcnt(8)" ::: "memory");
        __builtin_amdgcn_s_barrier();
        COMPUTE(kt % 3);
    }
    // tail: tiles 14,15 already staged; drain 4 then 0
    asm volatile("s_waitcnt vmcnt(4)" ::: "memory");
    __builtin_amdgcn_s_barrier();
    COMPUTE(14 % 3);
    asm volatile("s_waitcnt vmcnt(0)" ::: "memory");
    __builtin_amdgcn_s_barrier();
    COMPUTE(15 % 3);

    // Epilogue: clamp + scale + NT dwordx4 stores. Fragment (mi,ni): lane lr
    // is M-row mbase+mi*16+lr, regs are N-cols nbase+ni*16+lg*4 .. +3.
    // NCLS % 16 == 0, so the N-edge guard is fragment-granular.
    const int mbase = brow * 128 + wrow * 64;
    const int nbase = bcol * 128 + wcol * 64;
    #pragma unroll
    for (int mi = 0; mi < 4; ++mi) {
        const int grow = mbase + mi * 16 + lr;
        float* crow = C + (size_t)grow * NCLS;
        #pragma unroll
        for (int ni = 0; ni < 4; ++ni) {
            if (nbase + ni * 16 < NCLS) {
                f32x4 v = acc[mi][ni];
                f32x4 o;
                #pragma unroll
                for (int j = 0; j < 4; ++j) {
                    float cc = fminf(fmaxf(v[j], -1.0f + 1e-7f), 1.0f - 1e-7f);
                    o[j] = cc * SCALE_;
                }
                __builtin_nontemporal_store(o,
                    (f32x4*)&crow[nbase + ni * 16 + lg * 4]);
            }
        }
    }
#undef STAGE
#undef COMPUTE
}

extern "C" void kernel_launch(void* const* d_in, const int* in_sizes, int n_in,
                              void* d_out, int out_size, void* d_ws, size_t ws_size,
                              hipStream_t stream)
{
    const float* emb    = (const float*)d_in[0];
    const int*   labels = (const int*)d_in[1];
    const float* wgt    = (const float*)d_in[2];
    float*       out    = (float*)d_out;

    // workspace layout: [Ebf: 1024*512 bf16 = 1 MB][Wbf: 100096*512 bf16 = 102.5 MB]
    ushort* Ebf = (ushort*)d_ws;
    ushort* Wbf = (ushort*)((char*)d_ws + (size_t)BATCH * EDIM * 2);

    norm_rows_kernel<<<BATCH / 4, 256, 0, stream>>>(emb, Ebf, BATCH, BATCH);
    norm_rows_kernel<<<NPAD / 4, 256, 0, stream>>>(wgt, Wbf, NCLS, NPAD);

    gemm_arc_kernel<<<(BATCH / 128) * (NPAD / 128), 256, 0, stream>>>(Ebf, Wbf, out);

    fixup_labels_kernel<<<BATCH / 256, 256, 0, stream>>>(labels, out);
}